// Round 1
// baseline (1029.476 us; speedup 1.0000x reference)
//
#include <hip/hip_runtime.h>
#include <cstdint>
#include <cstddef>

// Problem constants
#define LSEQ 2048
#define BB   32
#define DD   1024
#define NLAYERS 4
#define MM   (LSEQ*BB)      // 65536 rows
#define BD   (BB*DD)        // 32768
#define CHUNK 32
#define NCHUNK (LSEQ/CHUNK) // 64

typedef _Float16 f16;
typedef __attribute__((ext_vector_type(8))) _Float16 f16x8;
typedef __attribute__((ext_vector_type(4))) float f32x4;

// ---------------- scan: h[t] = a*h[t-1] + x[t], a = exp(A_log[d]) ----------------

__global__ void scan_pass1(const float* __restrict__ x, const float* __restrict__ Alog,
                           f16* __restrict__ h, float* __restrict__ carry) {
    int tid = blockIdx.x * blockDim.x + threadIdx.x;   // 2M threads
    int bd  = tid & (BD - 1);
    int c   = tid >> 15;                               // chunk id
    float a = expf(Alog[bd & (DD - 1)]);
    size_t base = (size_t)c * CHUNK * BD + bd;
    float hv = 0.f;
#pragma unroll
    for (int i = 0; i < CHUNK; ++i) {
        hv = a * hv + x[base + (size_t)i * BD];
        h[base + (size_t)i * BD] = (f16)hv;
    }
    carry[c * BD + bd] = hv;
}

__global__ void scan_pass2(const float* __restrict__ Alog, float* __restrict__ carry) {
    int bd = blockIdx.x * blockDim.x + threadIdx.x;    // 32768 threads
    float d32 = expf((float)CHUNK * Alog[bd & (DD - 1)]);  // a^CHUNK
    float cin = 0.f;
    for (int c = 0; c < NCHUNK; ++c) {
        float co = carry[c * BD + bd];
        carry[c * BD + bd] = cin;       // exclusive carry-in
        cin = d32 * cin + co;
    }
}

__global__ void scan_pass3(const float* __restrict__ Alog, const float* __restrict__ carry,
                           f16* __restrict__ h) {
    int tid = blockIdx.x * blockDim.x + threadIdx.x;
    int bd  = tid & (BD - 1);
    int c   = tid >> 15;
    float a   = expf(Alog[bd & (DD - 1)]);
    float cin = carry[c * BD + bd];
    size_t base = (size_t)c * CHUNK * BD + bd;
    float p = a;
#pragma unroll
    for (int i = 0; i < CHUNK; ++i) {
        size_t idx = base + (size_t)i * BD;
        float hv = (float)h[idx] + p * cin;
        h[idx] = (f16)hv;
        p *= a;
    }
}

// ---------------- fp32 -> fp16 weight conversion ----------------

__global__ void cvt_w(const float* __restrict__ w, f16* __restrict__ o, int n) {
    int i = (blockIdx.x * blockDim.x + threadIdx.x) * 4;
    if (i + 3 < n) {
        float4 v = *(const float4*)&w[i];
        o[i + 0] = (f16)v.x; o[i + 1] = (f16)v.y;
        o[i + 2] = (f16)v.z; o[i + 3] = (f16)v.w;
    }
}

// ---------------- GEMM + bias + tanh:  C[m][n] = tanh(sum_k A[m][k]*W[n][k] + b[n]) ----------------
// A: [MM][1024] f16 row-major.  W: [1024][1024] f16 row-major (output-channel major, K contiguous).
// tile 128x128, BK=32, 256 threads = 4 waves in 2x2, wave tile 64x64, mfma 16x16x32 f16.

#define BM 128
#define BN 128
#define BK 32
#define KK 1024
#define NN 1024

__device__ __forceinline__ void gload_lds16(const void* g, void* l) {
    __builtin_amdgcn_global_load_lds((const __attribute__((address_space(1))) unsigned int*)g,
                                     (__attribute__((address_space(3))) unsigned int*)l,
                                     16, 0, 0);
}

__global__ __launch_bounds__(256) void gemm_tanh(const f16* __restrict__ A,
                                                 const f16* __restrict__ W,
                                                 const float* __restrict__ bias,
                                                 f16* __restrict__ C) {
    __shared__ f16 As[BM * BK];   // 8 KB
    __shared__ f16 Bs[BN * BK];   // 8 KB

    const int lane = threadIdx.x & 63;
    const int wid  = threadIdx.x >> 6;       // 0..3
    const int wrow = wid >> 1;               // 0..1
    const int wcol = wid & 1;                // 0..1
    const int tm = blockIdx.y * BM;
    const int tn = blockIdx.x * BN;

    const int srow = lane >> 2;              // 0..15, row within 16-row slab
    const int skof = (lane & 3) * 8;         // f16 k-offset 0,8,16,24

    f32x4 acc[4][4];
#pragma unroll
    for (int i = 0; i < 4; ++i)
#pragma unroll
        for (int j = 0; j < 4; ++j)
            acc[i][j] = (f32x4){0.f, 0.f, 0.f, 0.f};

    for (int kt = 0; kt < KK / BK; ++kt) {
        const int k0 = kt * BK;
        // stage A and B tiles: each wave issues 2+2 global_load_lds (1KB each)
#pragma unroll
        for (int j = 0; j < 2; ++j) {
            const int br = (wid * 2 + j) * 16;           // base row 0..112
            gload_lds16(A + (size_t)(tm + br + srow) * KK + k0 + skof, &As[br * BK]);
            gload_lds16(W + (size_t)(tn + br + srow) * KK + k0 + skof, &Bs[br * BK]);
        }
        __syncthreads();

        f16x8 af[4], bf[4];
#pragma unroll
        for (int mi = 0; mi < 4; ++mi)
            af[mi] = *(const f16x8*)&As[(wrow * 64 + mi * 16 + (lane & 15)) * BK + (lane >> 4) * 8];
#pragma unroll
        for (int ni = 0; ni < 4; ++ni)
            bf[ni] = *(const f16x8*)&Bs[(wcol * 64 + ni * 16 + (lane & 15)) * BK + (lane >> 4) * 8];
#pragma unroll
        for (int mi = 0; mi < 4; ++mi)
#pragma unroll
            for (int ni = 0; ni < 4; ++ni)
                acc[mi][ni] = __builtin_amdgcn_mfma_f32_16x16x32_f16(af[mi], bf[ni], acc[mi][ni], 0, 0, 0);
        __syncthreads();
    }

    // epilogue: bias + tanh, store f16
#pragma unroll
    for (int mi = 0; mi < 4; ++mi) {
        const int r0 = tm + wrow * 64 + mi * 16 + ((lane >> 4) << 2);
#pragma unroll
        for (int ni = 0; ni < 4; ++ni) {
            const int c = tn + wcol * 64 + ni * 16 + (lane & 15);
            const float bv = bias[c];
#pragma unroll
            for (int q = 0; q < 4; ++q) {
                float z = acc[mi][ni][q] + bv;
                C[(size_t)(r0 + q) * NN + c] = (f16)tanhf(z);
            }
        }
    }
}

// ---------------- head: out[m] = sum_d h[m][d]*hw[d] + hb ----------------

__global__ void head_k(const f16* __restrict__ h, const float* __restrict__ hw,
                       const float* __restrict__ hb, float* __restrict__ out) {
    const int row  = blockIdx.x * 4 + (threadIdx.x >> 6);
    const int lane = threadIdx.x & 63;
    const f16* hr = h + (size_t)row * DD;
    float s = 0.f;
#pragma unroll
    for (int j = 0; j < DD / 64; ++j) {
        int d = lane + j * 64;
        s += (float)hr[d] * hw[d];
    }
#pragma unroll
    for (int o = 32; o > 0; o >>= 1) s += __shfl_down(s, o, 64);
    if (lane == 0) out[row] = s + hb[0];
}

// ---------------- launch ----------------

extern "C" void kernel_launch(void* const* d_in, const int* in_sizes, int n_in,
                              void* d_out, int out_size, void* d_ws, size_t ws_size,
                              hipStream_t stream) {
    const float* x    = (const float*)d_in[0];
    const float* Alog = (const float*)d_in[1];
    const float* Wls  = (const float*)d_in[2];
    const float* bls  = (const float*)d_in[3];
    const float* hw   = (const float*)d_in[4];
    const float* hb   = (const float*)d_in[5];
    float* out = (float*)d_out;

    char* ws = (char*)d_ws;
    const size_t hbytes = (size_t)MM * DD * sizeof(f16);   // 128 MiB
    f16* h0 = (f16*)ws;
    f16* h1 = (f16*)(ws + hbytes);
    char* scratch = ws + 2 * hbytes;
    float* carry = (float*)scratch;                         // 8 MiB, scan phase only
    f16*   wf    = (f16*)scratch;                           // 8 MiB, reused after scan

    // 1. scan (chunked, 3 passes)
    scan_pass1<<<(NCHUNK * BD) / 256, 256, 0, stream>>>(x, Alog, h0, carry);
    scan_pass2<<<BD / 256, 256, 0, stream>>>(Alog, carry);
    scan_pass3<<<(NCHUNK * BD) / 256, 256, 0, stream>>>(Alog, carry, h0);

    // 2. weights fp32 -> fp16 (reuses carry region; stream-ordered after pass3)
    cvt_w<<<(NLAYERS * DD * DD / 4) / 256, 256, 0, stream>>>(Wls, wf, NLAYERS * DD * DD);

    // 3. four layers, ping-pong
    dim3 grid(NN / BN, MM / BM), blk(256);
    gemm_tanh<<<grid, blk, 0, stream>>>(h0, wf + 0 * (DD * DD), bls + 0 * DD, h1);
    gemm_tanh<<<grid, blk, 0, stream>>>(h1, wf + 1 * (DD * DD), bls + 1 * DD, h0);
    gemm_tanh<<<grid, blk, 0, stream>>>(h0, wf + 2 * (DD * DD), bls + 2 * DD, h1);
    gemm_tanh<<<grid, blk, 0, stream>>>(h1, wf + 3 * (DD * DD), bls + 3 * DD, h0);

    // 4. head
    head_k<<<MM / 4, 256, 0, stream>>>(h0, hw, hb, out);
}

// Round 2
// 940.309 us; speedup vs baseline: 1.0948x; 1.0948x over previous
//
#include <hip/hip_runtime.h>
#include <cstdint>
#include <cstddef>

// Problem constants
#define LSEQ 2048
#define BB   32
#define DD   1024
#define NLAYERS 4
#define MM   (LSEQ*BB)      // 65536 rows
#define BD   (BB*DD)        // 32768
#define CHUNK 32
#define NCHUNK (LSEQ/CHUNK) // 64

typedef _Float16 f16;
typedef __attribute__((ext_vector_type(8))) _Float16 f16x8;
typedef __attribute__((ext_vector_type(4))) float f32x4;

// ---------------- scan: h[t] = a*h[t-1] + x[t], a = exp(A_log[d]) ----------------

__global__ void scan_pass1(const float* __restrict__ x, const float* __restrict__ Alog,
                           f16* __restrict__ h, float* __restrict__ carry) {
    int tid = blockIdx.x * blockDim.x + threadIdx.x;   // 2M threads
    int bd  = tid & (BD - 1);
    int c   = tid >> 15;                               // chunk id
    float a = expf(Alog[bd & (DD - 1)]);
    size_t base = (size_t)c * CHUNK * BD + bd;
    float hv = 0.f;
#pragma unroll
    for (int i = 0; i < CHUNK; ++i) {
        hv = a * hv + x[base + (size_t)i * BD];
        h[base + (size_t)i * BD] = (f16)hv;
    }
    carry[c * BD + bd] = hv;
}

__global__ void scan_pass2(const float* __restrict__ Alog, float* __restrict__ carry) {
    int bd = blockIdx.x * blockDim.x + threadIdx.x;    // 32768 threads
    float d32 = expf((float)CHUNK * Alog[bd & (DD - 1)]);  // a^CHUNK
    float cin = 0.f;
    for (int c = 0; c < NCHUNK; ++c) {
        float co = carry[c * BD + bd];
        carry[c * BD + bd] = cin;       // exclusive carry-in
        cin = d32 * cin + co;
    }
}

__global__ void scan_pass3(const float* __restrict__ Alog, const float* __restrict__ carry,
                           f16* __restrict__ h) {
    int tid = blockIdx.x * blockDim.x + threadIdx.x;
    int bd  = tid & (BD - 1);
    int c   = tid >> 15;
    float a   = expf(Alog[bd & (DD - 1)]);
    float cin = carry[c * BD + bd];
    size_t base = (size_t)c * CHUNK * BD + bd;
    float p = a;
#pragma unroll
    for (int i = 0; i < CHUNK; ++i) {
        size_t idx = base + (size_t)i * BD;
        float hv = (float)h[idx] + p * cin;
        h[idx] = (f16)hv;
        p *= a;
    }
}

// ---------------- fp32 -> fp16 weight conversion ----------------

__global__ void cvt_w(const float* __restrict__ w, f16* __restrict__ o, int n) {
    int i = (blockIdx.x * blockDim.x + threadIdx.x) * 4;
    if (i + 3 < n) {
        float4 v = *(const float4*)&w[i];
        o[i + 0] = (f16)v.x; o[i + 1] = (f16)v.y;
        o[i + 2] = (f16)v.z; o[i + 3] = (f16)v.w;
    }
}

// ---------------- GEMM + bias + tanh:  C[m][n] = tanh(sum_k A[m][k]*W[n][k] + b[n]) ----------------
// A: [MM][1024] f16 row-major.  W: [1024][1024] f16 row-major (output-channel major, K contiguous).
// tile 128x128, BK=32, 256 threads = 4 waves in 2x2, wave tile 64x64, mfma 16x16x32 f16.
// 1-D grid of 4096 blocks; XCD-chunked swizzle (T1, m204 bijective; 4096%8==0):
// each XCD owns 64 contiguous M-panels, all 8 N-tiles of each panel run
// back-to-back on that XCD -> A panel is an L2 hit for 7 of 8 blocks.

#define BM 128
#define BN 128
#define BK 32
#define KK 1024
#define NN 1024
#define NTILES_N (NN / BN)   // 8

__device__ __forceinline__ void gload_lds16(const void* g, void* l) {
    __builtin_amdgcn_global_load_lds((const __attribute__((address_space(1))) unsigned int*)g,
                                     (__attribute__((address_space(3))) unsigned int*)l,
                                     16, 0, 0);
}

__global__ __launch_bounds__(256) void gemm_tanh(const f16* __restrict__ A,
                                                 const f16* __restrict__ W,
                                                 const float* __restrict__ bias,
                                                 f16* __restrict__ C) {
    __shared__ f16 As[BM * BK];   // 8 KB
    __shared__ f16 Bs[BN * BK];   // 8 KB

    const int lane = threadIdx.x & 63;
    const int wid  = threadIdx.x >> 6;       // 0..3
    const int wrow = wid >> 1;               // 0..1
    const int wcol = wid & 1;                // 0..1

    // T1: XCD-chunked bijective swizzle (HW round-robins blockIdx.x % 8 -> XCD)
    const int cpx = gridDim.x >> 3;                          // blocks per XCD chunk
    const int lin = (blockIdx.x & 7) * cpx + (blockIdx.x >> 3);
    const int tm  = (lin >> 3) * BM;                         // M-panel (slow within XCD)
    const int tn  = (lin & (NTILES_N - 1)) * BN;             // N-tile  (fast within XCD)

    const int srow = lane >> 2;              // 0..15, row within 16-row slab
    const int skof = (lane & 3) * 8;         // f16 k-offset 0,8,16,24

    f32x4 acc[4][4];
#pragma unroll
    for (int i = 0; i < 4; ++i)
#pragma unroll
        for (int j = 0; j < 4; ++j)
            acc[i][j] = (f32x4){0.f, 0.f, 0.f, 0.f};

    for (int kt = 0; kt < KK / BK; ++kt) {
        const int k0 = kt * BK;
        // stage A and B tiles: each wave issues 2+2 global_load_lds (1KB each)
#pragma unroll
        for (int j = 0; j < 2; ++j) {
            const int br = (wid * 2 + j) * 16;           // base row 0..112
            gload_lds16(A + (size_t)(tm + br + srow) * KK + k0 + skof, &As[br * BK]);
            gload_lds16(W + (size_t)(tn + br + srow) * KK + k0 + skof, &Bs[br * BK]);
        }
        __syncthreads();

        f16x8 af[4], bf[4];
#pragma unroll
        for (int mi = 0; mi < 4; ++mi)
            af[mi] = *(const f16x8*)&As[(wrow * 64 + mi * 16 + (lane & 15)) * BK + (lane >> 4) * 8];
#pragma unroll
        for (int ni = 0; ni < 4; ++ni)
            bf[ni] = *(const f16x8*)&Bs[(wcol * 64 + ni * 16 + (lane & 15)) * BK + (lane >> 4) * 8];
#pragma unroll
        for (int mi = 0; mi < 4; ++mi)
#pragma unroll
            for (int ni = 0; ni < 4; ++ni)
                acc[mi][ni] = __builtin_amdgcn_mfma_f32_16x16x32_f16(af[mi], bf[ni], acc[mi][ni], 0, 0, 0);
        __syncthreads();
    }

    // epilogue: bias + tanh, store f16
#pragma unroll
    for (int mi = 0; mi < 4; ++mi) {
        const int r0 = tm + wrow * 64 + mi * 16 + ((lane >> 4) << 2);
#pragma unroll
        for (int ni = 0; ni < 4; ++ni) {
            const int c = tn + wcol * 64 + ni * 16 + (lane & 15);
            const float bv = bias[c];
#pragma unroll
            for (int q = 0; q < 4; ++q) {
                float z = acc[mi][ni][q] + bv;
                C[(size_t)(r0 + q) * NN + c] = (f16)tanhf(z);
            }
        }
    }
}

// ---------------- head: out[m] = sum_d h[m][d]*hw[d] + hb ----------------

__global__ void head_k(const f16* __restrict__ h, const float* __restrict__ hw,
                       const float* __restrict__ hb, float* __restrict__ out) {
    const int row  = blockIdx.x * 4 + (threadIdx.x >> 6);
    const int lane = threadIdx.x & 63;
    const f16* hr = h + (size_t)row * DD;
    float s = 0.f;
#pragma unroll
    for (int j = 0; j < DD / 64; ++j) {
        int d = lane + j * 64;
        s += (float)hr[d] * hw[d];
    }
#pragma unroll
    for (int o = 32; o > 0; o >>= 1) s += __shfl_down(s, o, 64);
    if (lane == 0) out[row] = s + hb[0];
}

// ---------------- launch ----------------

extern "C" void kernel_launch(void* const* d_in, const int* in_sizes, int n_in,
                              void* d_out, int out_size, void* d_ws, size_t ws_size,
                              hipStream_t stream) {
    const float* x    = (const float*)d_in[0];
    const float* Alog = (const float*)d_in[1];
    const float* Wls  = (const float*)d_in[2];
    const float* bls  = (const float*)d_in[3];
    const float* hw   = (const float*)d_in[4];
    const float* hb   = (const float*)d_in[5];
    float* out = (float*)d_out;

    char* ws = (char*)d_ws;
    const size_t hbytes = (size_t)MM * DD * sizeof(f16);   // 128 MiB
    f16* h0 = (f16*)ws;
    f16* h1 = (f16*)(ws + hbytes);
    char* scratch = ws + 2 * hbytes;
    float* carry = (float*)scratch;                         // 8 MiB, scan phase only
    f16*   wf    = (f16*)scratch;                           // 8 MiB, reused after scan

    // 1. scan (chunked, 3 passes)
    scan_pass1<<<(NCHUNK * BD) / 256, 256, 0, stream>>>(x, Alog, h0, carry);
    scan_pass2<<<BD / 256, 256, 0, stream>>>(Alog, carry);
    scan_pass3<<<(NCHUNK * BD) / 256, 256, 0, stream>>>(Alog, carry, h0);

    // 2. weights fp32 -> fp16 (reuses carry region; stream-ordered after pass3)
    cvt_w<<<(NLAYERS * DD * DD / 4) / 256, 256, 0, stream>>>(Wls, wf, NLAYERS * DD * DD);

    // 3. four layers, ping-pong (1-D grid, XCD swizzle inside kernel)
    dim3 grid((MM / BM) * (NN / BN)), blk(256);
    gemm_tanh<<<grid, blk, 0, stream>>>(h0, wf + 0 * (DD * DD), bls + 0 * DD, h1);
    gemm_tanh<<<grid, blk, 0, stream>>>(h1, wf + 1 * (DD * DD), bls + 1 * DD, h0);
    gemm_tanh<<<grid, blk, 0, stream>>>(h0, wf + 2 * (DD * DD), bls + 2 * DD, h1);
    gemm_tanh<<<grid, blk, 0, stream>>>(h1, wf + 3 * (DD * DD), bls + 3 * DD, h0);

    // 4. head
    head_k<<<MM / 4, 256, 0, stream>>>(h0, hw, hb, out);
}